// Round 1
// baseline (83.470 us; speedup 1.0000x reference)
//
#include <hip/hip_runtime.h>

typedef __bf16 bf16x8 __attribute__((ext_vector_type(8)));
typedef float f32x4 __attribute__((ext_vector_type(4)));

__device__ __forceinline__ f32x4 mfma16(bf16x8 a, bf16x8 b, f32x4 c) {
    return __builtin_amdgcn_mfma_f32_16x16x32_bf16(a, b, c, 0, 0, 0);
}

// Fused 3-layer MLP: out = (relu(relu(x@W0^T + b0)@W1^T + b1))@W2^T + b2
// x: [N,64] f32, W0:[64,64], W1:[64,64], W2:[32,64], out: [N,32] f32.
// bf16 MFMA compute, fp32 accumulate. Each wave: 4 M-tiles of 16 nodes.
__global__ __launch_bounds__(256) void cheb_mlp_kernel(
    const float* __restrict__ x,
    const float* __restrict__ W0, const float* __restrict__ b0v,
    const float* __restrict__ W1, const float* __restrict__ b1v,
    const float* __restrict__ W2, const float* __restrict__ b2v,
    float* __restrict__ out, int n_nodes)
{
    // Padded rows (72 = 64 + 8 elems = +16B) keep ds_read_b128 conflicts <= 2-way.
    __shared__ __bf16 w0s[64][72];
    __shared__ __bf16 w1s[64][72];
    __shared__ __bf16 w2s[32][72];
    __shared__ float bias0[64];
    __shared__ float bias1[64];
    __shared__ float bias2[32];
    __shared__ __bf16 hbuf[4][16][72];   // per-wave activation staging

    const int tid = threadIdx.x;

    // One-time weight convert fp32 -> bf16 into LDS.
    for (int i = tid; i < 64 * 64; i += 256) {
        int r = i >> 6, c = i & 63;
        w0s[r][c] = (__bf16)W0[i];
        w1s[r][c] = (__bf16)W1[i];
    }
    for (int i = tid; i < 32 * 64; i += 256) {
        int r = i >> 6, c = i & 63;
        w2s[r][c] = (__bf16)W2[i];
    }
    if (tid < 64) { bias0[tid] = b0v[tid]; bias1[tid] = b1v[tid]; }
    if (tid >= 64 && tid < 96) bias2[tid - 64] = b2v[tid - 64];
    __syncthreads();

    const int wave = tid >> 6;
    const int lane = tid & 63;
    const int lr = lane & 15;   // A-row / B-col / C-col within 16-tile
    const int lg = lane >> 4;   // quarter-wave group: k-offset = 8*lg, C-row = 4*lg + r

    // Hoist all weight B-fragments into registers (once per block).
    // B[k][n] = W[n][k]; lane needs W[16t+lr][32s + 8*lg + j], j=0..7 (16B contiguous).
    bf16x8 fw0[4][2], fw1[4][2], fw2[2][2];
#pragma unroll
    for (int t = 0; t < 4; ++t)
#pragma unroll
        for (int s = 0; s < 2; ++s) {
            fw0[t][s] = *(const bf16x8*)&w0s[t * 16 + lr][s * 32 + lg * 8];
            fw1[t][s] = *(const bf16x8*)&w1s[t * 16 + lr][s * 32 + lg * 8];
        }
#pragma unroll
    for (int t = 0; t < 2; ++t)
#pragma unroll
        for (int s = 0; s < 2; ++s)
            fw2[t][s] = *(const bf16x8*)&w2s[t * 16 + lr][s * 32 + lg * 8];

    const int wave_base = blockIdx.x * 256 + wave * 64;

    f32x4 cx0, cx1, cx2, cx3;
    const float* xbase = x + (size_t)lr * 64 + lg * 8;
    if (wave_base < n_nodes) {
        const float* xp = xbase + (size_t)wave_base * 64;
        cx0 = *(const f32x4*)(xp);
        cx1 = *(const f32x4*)(xp + 4);
        cx2 = *(const f32x4*)(xp + 32);
        cx3 = *(const f32x4*)(xp + 36);
    }

#pragma unroll
    for (int mt = 0; mt < 4; ++mt) {
        const int m_cur = wave_base + mt * 16;
        if (m_cur >= n_nodes) break;

        // Prefetch next M-tile (1-deep) to hide HBM latency under compute.
        f32x4 nx0, nx1, nx2, nx3;
        const bool has_next = (mt < 3) && (m_cur + 16 < n_nodes);
        if (has_next) {
            const float* xp = xbase + (size_t)(m_cur + 16) * 64;
            nx0 = *(const f32x4*)(xp);
            nx1 = *(const f32x4*)(xp + 4);
            nx2 = *(const f32x4*)(xp + 32);
            nx3 = *(const f32x4*)(xp + 36);
        }

        // ---- layer 0: A-fragment straight from registers (x, fp32->bf16) ----
        bf16x8 ax0, ax1;
#pragma unroll
        for (int j = 0; j < 4; ++j) {
            ax0[j]     = (__bf16)cx0[j];
            ax0[j + 4] = (__bf16)cx1[j];
            ax1[j]     = (__bf16)cx2[j];
            ax1[j + 4] = (__bf16)cx3[j];
        }
        f32x4 acc[4];
#pragma unroll
        for (int t = 0; t < 4; ++t) {
            acc[t] = f32x4{0.f, 0.f, 0.f, 0.f};
            acc[t] = mfma16(ax0, fw0[t][0], acc[t]);
            acc[t] = mfma16(ax1, fw0[t][1], acc[t]);
        }
        // bias + relu, stage H0 (bf16) for re-layout. C/D: row=4*lg+r, col=16t+lr.
#pragma unroll
        for (int t = 0; t < 4; ++t) {
            const float bv = bias0[t * 16 + lr];
#pragma unroll
            for (int r = 0; r < 4; ++r) {
                float v = acc[t][r] + bv;
                v = v > 0.f ? v : 0.f;
                hbuf[wave][lg * 4 + r][t * 16 + lr] = (__bf16)v;
            }
        }

        // ---- layer 1 ----
        bf16x8 ah0 = *(const bf16x8*)&hbuf[wave][lr][lg * 8];
        bf16x8 ah1 = *(const bf16x8*)&hbuf[wave][lr][32 + lg * 8];
#pragma unroll
        for (int t = 0; t < 4; ++t) {
            acc[t] = f32x4{0.f, 0.f, 0.f, 0.f};
            acc[t] = mfma16(ah0, fw1[t][0], acc[t]);
            acc[t] = mfma16(ah1, fw1[t][1], acc[t]);
        }
#pragma unroll
        for (int t = 0; t < 4; ++t) {
            const float bv = bias1[t * 16 + lr];
#pragma unroll
            for (int r = 0; r < 4; ++r) {
                float v = acc[t][r] + bv;
                v = v > 0.f ? v : 0.f;
                hbuf[wave][lg * 4 + r][t * 16 + lr] = (__bf16)v;
            }
        }

        // ---- layer 2 (no relu) + store ----
        bf16x8 ag0 = *(const bf16x8*)&hbuf[wave][lr][lg * 8];
        bf16x8 ag1 = *(const bf16x8*)&hbuf[wave][lr][32 + lg * 8];
        f32x4 acc2[2];
#pragma unroll
        for (int t = 0; t < 2; ++t) {
            acc2[t] = f32x4{0.f, 0.f, 0.f, 0.f};
            acc2[t] = mfma16(ag0, fw2[t][0], acc2[t]);
            acc2[t] = mfma16(ag1, fw2[t][1], acc2[t]);
        }
#pragma unroll
        for (int t = 0; t < 2; ++t) {
            const float bv = bias2[t * 16 + lr];
#pragma unroll
            for (int r = 0; r < 4; ++r) {
                out[(size_t)(m_cur + lg * 4 + r) * 32 + t * 16 + lr] = acc2[t][r] + bv;
            }
        }

        if (has_next) { cx0 = nx0; cx1 = nx1; cx2 = nx2; cx3 = nx3; }
    }
}

extern "C" void kernel_launch(void* const* d_in, const int* in_sizes, int n_in,
                              void* d_out, int out_size, void* d_ws, size_t ws_size,
                              hipStream_t stream) {
    const float* x  = (const float*)d_in[0];
    // d_in[1] = edge_index (int64), d_in[2] = edge_weight — dead inputs for K=1 ChebConv.
    const float* W0 = (const float*)d_in[3];
    const float* b0 = (const float*)d_in[4];
    const float* W1 = (const float*)d_in[5];
    const float* b1 = (const float*)d_in[6];
    const float* W2 = (const float*)d_in[7];
    const float* b2 = (const float*)d_in[8];
    float* out = (float*)d_out;

    const int n_nodes = in_sizes[0] / 64;           // 1,000,000
    const int grid = (n_nodes + 255) / 256;         // 256 nodes per block
    cheb_mlp_kernel<<<grid, 256, 0, stream>>>(x, W0, b0, W1, b1, W2, b2, out, n_nodes);
}